// Round 5
// baseline (1969.210 us; speedup 1.0000x reference)
//
#include <hip/hip_runtime.h>

typedef unsigned short u16;
typedef __attribute__((ext_vector_type(8))) short s16x8;
typedef __attribute__((ext_vector_type(4))) float f32x4;

__device__ __forceinline__ float bf2f(u16 u) {
    union { unsigned int i; float f; } c; c.i = ((unsigned int)u) << 16; return c.f;
}
__device__ __forceinline__ u16 f2bf(float f) {
    union { float f; unsigned int u; } c; c.f = f;
    unsigned int u = c.u;
    unsigned int r = (u + 0x7fffu + ((u >> 16) & 1u)) >> 16;
    return (u16)r;
}

// ------------- transpose fp32 -> fp32, 32x32 tiles -------------
__global__ __launch_bounds__(256) void transpose_f2f_kernel(const float* __restrict__ src,
                                                            float* __restrict__ dst,
                                                            int R, int C) {
    __shared__ float tile[32][33];
    src += (size_t)blockIdx.z * R * C;
    dst += (size_t)blockIdx.z * R * C;
    int c0 = blockIdx.x * 32, r0 = blockIdx.y * 32;
    int tx = threadIdx.x & 31, ty = threadIdx.x >> 5;
    for (int i = 0; i < 4; i++)
        tile[ty + 8 * i][tx] = src[(size_t)(r0 + ty + 8 * i) * C + c0 + tx];
    __syncthreads();
    for (int i = 0; i < 4; i++)
        dst[(size_t)(c0 + ty + 8 * i) * R + r0 + tx] = tile[tx][ty + 8 * i];
}

// ------------- transpose fp32 -> bf16, 32x32 tiles, batched via blockIdx.z -------------
__global__ __launch_bounds__(256) void transpose_f2b_kernel(const float* __restrict__ src,
                                                            u16* __restrict__ dst,
                                                            int R, int C) {
    __shared__ float tile[32][33];
    src += (size_t)blockIdx.z * R * C;
    dst += (size_t)blockIdx.z * R * C;
    int c0 = blockIdx.x * 32, r0 = blockIdx.y * 32;
    int tx = threadIdx.x & 31, ty = threadIdx.x >> 5;
    for (int i = 0; i < 4; i++)
        tile[ty + 8 * i][tx] = src[(size_t)(r0 + ty + 8 * i) * C + c0 + tx];
    __syncthreads();
    for (int i = 0; i < 4; i++)
        dst[(size_t)(c0 + ty + 8 * i) * R + r0 + tx] = f2bf(tile[tx][ty + 8 * i]);
}

// ------------- layernorm fp32 -> fp32 (attention trunk: precision matters) -------------
__global__ __launch_bounds__(256) void ln_f32_kernel(const float* __restrict__ x,
                                                     const float* __restrict__ sc,
                                                     const float* __restrict__ bi,
                                                     float* __restrict__ out) {
    int row = blockIdx.x, tid = threadIdx.x;
    f32x4 u = *(const f32x4*)(x + (size_t)row * 1024 + tid * 4);
    float s = u[0] + u[1] + u[2] + u[3];
    float ss = u[0]*u[0] + u[1]*u[1] + u[2]*u[2] + u[3]*u[3];
    for (int off = 1; off < 64; off <<= 1) { s += __shfl_xor(s, off, 64); ss += __shfl_xor(ss, off, 64); }
    __shared__ float red[8];
    if ((tid & 63) == 0) { red[tid >> 6] = s; red[4 + (tid >> 6)] = ss; }
    __syncthreads();
    s = red[0] + red[1] + red[2] + red[3];
    ss = red[4] + red[5] + red[6] + red[7];
    float mu = s * (1.0f / 1024.0f);
    float rstd = rsqrtf(ss * (1.0f / 1024.0f) - mu * mu + 1e-5f);
    f32x4 g = *(const f32x4*)(sc + tid * 4);
    f32x4 b = *(const f32x4*)(bi + tid * 4);
    float* op = out + (size_t)row * 1024 + tid * 4;
    for (int i = 0; i < 4; i++)
        op[i] = (u[i] - mu) * rstd * g[i] + b[i];
}

// ------------- layernorm fp32 -> bf16 (MoE expert-GEMM input) -------------
__global__ __launch_bounds__(256) void ln_f2b_kernel(const float* __restrict__ x,
                                                     const float* __restrict__ sc,
                                                     const float* __restrict__ bi,
                                                     u16* __restrict__ out) {
    int row = blockIdx.x, tid = threadIdx.x;
    f32x4 u = *(const f32x4*)(x + (size_t)row * 1024 + tid * 4);
    float s = u[0] + u[1] + u[2] + u[3];
    float ss = u[0]*u[0] + u[1]*u[1] + u[2]*u[2] + u[3]*u[3];
    for (int off = 1; off < 64; off <<= 1) { s += __shfl_xor(s, off, 64); ss += __shfl_xor(ss, off, 64); }
    __shared__ float red[8];
    if ((tid & 63) == 0) { red[tid >> 6] = s; red[4 + (tid >> 6)] = ss; }
    __syncthreads();
    s = red[0] + red[1] + red[2] + red[3];
    ss = red[4] + red[5] + red[6] + red[7];
    float mu = s * (1.0f / 1024.0f);
    float rstd = rsqrtf(ss * (1.0f / 1024.0f) - mu * mu + 1e-5f);
    f32x4 g = *(const f32x4*)(sc + tid * 4);
    f32x4 b = *(const f32x4*)(bi + tid * 4);
    u16* op = out + (size_t)row * 1024 + tid * 4;
    for (int i = 0; i < 4; i++)
        op[i] = f2bf((u[i] - mu) * rstd * g[i] + b[i]);
}

// ------------- split-fp32 GEMM: C[M,N] = A[M,K] @ BT[N,K]^T, fp32 in/out -------------
// fp32 operands split on the fly into bf16 hi+lo; acc = hi*hi + hi*lo + lo*hi
// (~1e-5 relative accuracy at 3x bf16-MFMA cost). 128x128 tile, BK=32, 4 waves.
// mode 0: C = acc          mode 1: C = acc + res[idx]
__global__ __launch_bounds__(256) void gemm_split(const float* __restrict__ A,
                                                  const float* __restrict__ BT,
                                                  int M, int N, int K,
                                                  float* __restrict__ C, int mode,
                                                  const float* __restrict__ res) {
    __shared__ __align__(16) short Ah[128 * 32], Al[128 * 32];
    __shared__ __align__(16) short Bh[128 * 32], Bl[128 * 32];
    int m0 = blockIdx.y * 128, n0 = blockIdx.x * 128;
    int tid = threadIdx.x, lane = tid & 63, w = tid >> 6;
    int wm = (w & 1) * 64, wn = (w >> 1) * 64;
    int lr = lane & 15, lq = lane >> 4;
    f32x4 acc[4][4] = {};

    for (int k0 = 0; k0 < K; k0 += 32) {
        for (int c = tid; c < 512; c += 256) {
            int row = c >> 2, col = (c & 3) * 8;
            const float* ap = &A[(size_t)(m0 + row) * K + k0 + col];
            const float* bp = &BT[(size_t)(n0 + row) * K + k0 + col];
            f32x4 a0 = *(const f32x4*)ap, a1 = *(const f32x4*)(ap + 4);
            f32x4 b0 = *(const f32x4*)bp, b1 = *(const f32x4*)(bp + 4);
            s16x8 ahv, alv, bhv, blv;
            for (int i = 0; i < 4; i++) {
                u16 h;
                h = f2bf(a0[i]); ahv[i]     = (short)h; alv[i]     = (short)f2bf(a0[i] - bf2f(h));
                h = f2bf(a1[i]); ahv[4 + i] = (short)h; alv[4 + i] = (short)f2bf(a1[i] - bf2f(h));
                h = f2bf(b0[i]); bhv[i]     = (short)h; blv[i]     = (short)f2bf(b0[i] - bf2f(h));
                h = f2bf(b1[i]); bhv[4 + i] = (short)h; blv[4 + i] = (short)f2bf(b1[i] - bf2f(h));
            }
            *(s16x8*)&Ah[row * 32 + col] = ahv;
            *(s16x8*)&Al[row * 32 + col] = alv;
            *(s16x8*)&Bh[row * 32 + col] = bhv;
            *(s16x8*)&Bl[row * 32 + col] = blv;
        }
        __syncthreads();
        s16x8 ah[4], al[4], bh[4], bl[4];
        for (int i = 0; i < 4; i++) {
            int off = (wm + i * 16 + lr) * 32 + lq * 8;
            ah[i] = *(const s16x8*)&Ah[off];
            al[i] = *(const s16x8*)&Al[off];
        }
        for (int j = 0; j < 4; j++) {
            int off = (wn + j * 16 + lr) * 32 + lq * 8;
            bh[j] = *(const s16x8*)&Bh[off];
            bl[j] = *(const s16x8*)&Bl[off];
        }
        for (int i = 0; i < 4; i++)
            for (int j = 0; j < 4; j++) {
                acc[i][j] = __builtin_amdgcn_mfma_f32_16x16x32_bf16(ah[i], bh[j], acc[i][j], 0, 0, 0);
                acc[i][j] = __builtin_amdgcn_mfma_f32_16x16x32_bf16(ah[i], bl[j], acc[i][j], 0, 0, 0);
                acc[i][j] = __builtin_amdgcn_mfma_f32_16x16x32_bf16(al[i], bh[j], acc[i][j], 0, 0, 0);
            }
        __syncthreads();
    }

    for (int i = 0; i < 4; i++)
        for (int j = 0; j < 4; j++)
            for (int r = 0; r < 4; r++) {
                int row = m0 + wm + i * 16 + lq * 4 + r;
                int col = n0 + wn + j * 16 + lr;
                size_t idx = (size_t)row * N + col;
                float v = acc[i][j][r];
                C[idx] = (mode == 0) ? v : v + res[idx];
            }
}

// ------------- bf16 GEMM (MoE): C[M,N] = A[M,K] @ BT[N,K]^T -------------
// mode 1: fp32 C = acc + res[idx]     mode 2: bf16 C = relu(acc)*gates[row][col>>8]
__global__ __launch_bounds__(256) void gemm_bt(const u16* __restrict__ A,
                                               const u16* __restrict__ BT,
                                               int M, int N, int K,
                                               void* __restrict__ C, int mode,
                                               const float* __restrict__ res,
                                               const float* __restrict__ gates) {
    __shared__ __align__(16) short As[128 * 32];
    __shared__ __align__(16) short Bs[128 * 32];
    int m0 = blockIdx.y * 128, n0 = blockIdx.x * 128;
    int tid = threadIdx.x, lane = tid & 63, w = tid >> 6;
    int wm = (w & 1) * 64, wn = (w >> 1) * 64;
    int lr = lane & 15, lq = lane >> 4;
    f32x4 acc[4][4] = {};

    for (int k0 = 0; k0 < K; k0 += 32) {
        for (int c = tid; c < 512; c += 256) {
            int row = c >> 2, col = (c & 3) * 8;
            *(s16x8*)&As[row * 32 + col] = *(const s16x8*)&A[(size_t)(m0 + row) * K + k0 + col];
            *(s16x8*)&Bs[row * 32 + col] = *(const s16x8*)&BT[(size_t)(n0 + row) * K + k0 + col];
        }
        __syncthreads();
        s16x8 av[4], bv[4];
        for (int i = 0; i < 4; i++) av[i] = *(const s16x8*)&As[(wm + i * 16 + lr) * 32 + lq * 8];
        for (int j = 0; j < 4; j++) bv[j] = *(const s16x8*)&Bs[(wn + j * 16 + lr) * 32 + lq * 8];
        for (int i = 0; i < 4; i++)
            for (int j = 0; j < 4; j++)
                acc[i][j] = __builtin_amdgcn_mfma_f32_16x16x32_bf16(av[i], bv[j], acc[i][j], 0, 0, 0);
        __syncthreads();
    }

    for (int i = 0; i < 4; i++)
        for (int j = 0; j < 4; j++)
            for (int r = 0; r < 4; r++) {
                int row = m0 + wm + i * 16 + lq * 4 + r;
                int col = n0 + wn + j * 16 + lr;
                size_t idx = (size_t)row * N + col;
                float v = acc[i][j][r];
                if (mode == 1) {
                    ((float*)C)[idx] = v + res[idx];
                } else {
                    float g = gates[(size_t)row * 16 + (col >> 8)];
                    ((u16*)C)[idx] = f2bf(fmaxf(v, 0.0f) * g);
                }
            }
}

// ------------- attention (fp32): one block = one (b,h) x 16-row Q tile, online softmax ----
__global__ __launch_bounds__(256) void attn_kernel(const float* __restrict__ q,
                                                   const float* __restrict__ kg,
                                                   const float* __restrict__ vg,
                                                   float* __restrict__ ctx) {
    __shared__ __align__(16) float qs[16][68];
    __shared__ __align__(16) float ks[64][68];
    __shared__ __align__(16) float vsT[64][68];
    __shared__ __align__(16) float ps[4][4][64];
    int bh = blockIdx.y;
    int b = bh >> 4, h = bh & 15;
    int q0 = blockIdx.x * 16;
    int tid = threadIdx.x, w = tid >> 6, lane = tid & 63;

    {   // load Q tile (scaled by 1/sqrt(64))
        int r = tid >> 4, dd = (tid & 15) * 4;
        f32x4 u = *(const f32x4*)(q + ((size_t)(b * 2048 + q0 + r)) * 1024 + h * 64 + dd);
        for (int i = 0; i < 4; i++) qs[r][dd + i] = u[i] * 0.125f;
    }
    float m_i[4], l_i[4], o_i[4];
    for (int i = 0; i < 4; i++) { m_i[i] = -1e30f; l_i[i] = 0.0f; o_i[i] = 0.0f; }

    for (int kc = 0; kc < 2048; kc += 64) {
        {   // stage K chunk and V^T chunk
            int j = tid >> 2, d0 = (tid & 3) * 16;
            const float* kp = kg + ((size_t)(b * 2048 + kc + j)) * 1024 + h * 64 + d0;
            const float* vp = vg + ((size_t)(b * 2048 + kc + j)) * 1024 + h * 64 + d0;
            for (int ii = 0; ii < 16; ii += 4) {
                f32x4 kv = *(const f32x4*)(kp + ii);
                f32x4 vv = *(const f32x4*)(vp + ii);
                for (int i = 0; i < 4; i++) { ks[j][d0 + ii + i] = kv[i]; vsT[d0 + ii + i][j] = vv[i]; }
            }
        }
        __syncthreads();
        // QK^T: lane = key j in chunk; wave w handles q-rows 4w..4w+3
        float s0 = 0, s1 = 0, s2 = 0, s3 = 0;
        int r0 = 4 * w;
        for (int d = 0; d < 64; d += 4) {
            f32x4 kv = *(const f32x4*)&ks[lane][d];
            f32x4 qa = *(const f32x4*)&qs[r0 + 0][d];
            f32x4 qb = *(const f32x4*)&qs[r0 + 1][d];
            f32x4 qc = *(const f32x4*)&qs[r0 + 2][d];
            f32x4 qd = *(const f32x4*)&qs[r0 + 3][d];
            s0 += kv[0]*qa[0] + kv[1]*qa[1] + kv[2]*qa[2] + kv[3]*qa[3];
            s1 += kv[0]*qb[0] + kv[1]*qb[1] + kv[2]*qb[2] + kv[3]*qb[3];
            s2 += kv[0]*qc[0] + kv[1]*qc[1] + kv[2]*qc[2] + kv[3]*qc[3];
            s3 += kv[0]*qd[0] + kv[1]*qd[1] + kv[2]*qd[2] + kv[3]*qd[3];
        }
        float sArr[4] = { s0, s1, s2, s3 };
        for (int i = 0; i < 4; i++) {
            float mx = sArr[i];
            for (int off = 32; off; off >>= 1) mx = fmaxf(mx, __shfl_xor(mx, off, 64));
            float mn = fmaxf(m_i[i], mx);
            float al = __expf(m_i[i] - mn);
            float p = __expf(sArr[i] - mn);
            float psum = p;
            for (int off = 32; off; off >>= 1) psum += __shfl_xor(psum, off, 64);
            l_i[i] = l_i[i] * al + psum;
            m_i[i] = mn;
            o_i[i] *= al;
            ps[w][i][lane] = p;
        }
        __syncthreads();
        // PV: lane = output dim c
        for (int jj = 0; jj < 64; jj += 4) {
            f32x4 vv = *(const f32x4*)&vsT[lane][jj];
            for (int i = 0; i < 4; i++) {
                f32x4 pv = *(const f32x4*)&ps[w][i][jj];
                o_i[i] += pv[0]*vv[0] + pv[1]*vv[1] + pv[2]*vv[2] + pv[3]*vv[3];
            }
        }
        __syncthreads();
    }
    for (int i = 0; i < 4; i++) {
        int r = q0 + 4 * w + i;
        ctx[((size_t)(b * 2048 + r)) * 1024 + h * 64 + lane] = o_i[i] / l_i[i];
    }
}

// ------------- router: pure fp32. One wave/token: LN2 from fp32 trunk, fp32 logits,
// sigmoid, top-2 -> dense gate table [T,16]. Decisions must match the fp32 reference. ----
__global__ __launch_bounds__(256) void router_kernel(const float* __restrict__ x2,
                                                     const float* __restrict__ sc,
                                                     const float* __restrict__ bi,
                                                     const float* __restrict__ Wsel,
                                                     float* __restrict__ gates) {
    int tid = threadIdx.x, w = tid >> 6, lane = tid & 63;
    int t = blockIdx.x * 4 + w;
    const float* xp = x2 + (size_t)t * 1024;
    float s = 0.0f, ss = 0.0f;
    for (int i = 0; i < 16; i++) {
        float v = xp[lane * 16 + i];
        s += v; ss += v * v;
    }
    for (int off = 1; off < 64; off <<= 1) { s += __shfl_xor(s, off, 64); ss += __shfl_xor(ss, off, 64); }
    float mu = s * (1.0f / 1024.0f);
    float rstd = rsqrtf(ss * (1.0f / 1024.0f) - mu * mu + 1e-5f);
    int e = lane & 15, part = lane >> 4;
    float acc = 0.0f;
    for (int d = part * 256; d < part * 256 + 256; d++) {
        float h = (xp[d] - mu) * rstd * sc[d] + bi[d];
        acc += h * Wsel[(size_t)d * 16 + e];
    }
    acc += __shfl_xor(acc, 16, 64);
    acc += __shfl_xor(acc, 32, 64);
    float v = 1.0f / (1.0f + __expf(-acc));
    float m1 = v;
    for (int off = 1; off < 64; off <<= 1) m1 = fmaxf(m1, __shfl_xor(m1, off, 64));
    unsigned long long b1 = __ballot(v == m1);
    int e1 = (__ffsll(b1) - 1) & 15;
    float v2 = (e == e1) ? -1e30f : v;
    float m2 = v2;
    for (int off = 1; off < 64; off <<= 1) m2 = fmaxf(m2, __shfl_xor(m2, off, 64));
    unsigned long long b2 = __ballot(v2 == m2);
    int e2 = (__ffsll(b2) - 1) & 15;
    if (lane < 16)
        gates[(size_t)t * 16 + e] = (e == e1) ? m1 : (e == e2 ? m2 : 0.0f);
}

extern "C" void kernel_launch(void* const* d_in, const int* in_sizes, int n_in,
                              void* d_out, int out_size, void* d_ws, size_t ws_size,
                              hipStream_t stream) {
    const float* x    = (const float*)d_in[0];
    const float* Wq   = (const float*)d_in[1];
    const float* Wk   = (const float*)d_in[2];
    const float* Wv   = (const float*)d_in[3];
    const float* Wo   = (const float*)d_in[4];
    const float* ln1s = (const float*)d_in[5];
    const float* ln1b = (const float*)d_in[6];
    const float* ln2s = (const float*)d_in[7];
    const float* ln2b = (const float*)d_in[8];
    const float* Wsel = (const float*)d_in[9];
    const float* W1   = (const float*)d_in[10];
    const float* W2   = (const float*)d_in[11];
    float* out = (float*)d_out;

    // Workspace layout (104.25 MB):
    //  [0,16)    h1 fp32 (ln1 out; reused as ctx fp32 after QKV)
    //  [16,32)   qb fp32 (dead after attn; reused as x2 fp32)
    //  [32,48)   kb fp32 ┐ dead after attn; reused as up bf16 [32,64)
    //  [48,64)   vb fp32 ┘
    //  [64,72)   h2 bf16 (ln2 out)
    //  [72,88)   WqT/WkT/WvT/WoT fp32 (4 MB each)
    //  [88,96)   W1T bf16
    //  [96,104)  W2T bf16
    //  [104,104.25) gates fp32 [4096,16]
    char* ws = (char*)d_ws;
    const size_t MB = 1024 * 1024;
    float* h1    = (float*)(ws + 0 * MB);
    float* qb    = (float*)(ws + 16 * MB);
    float* kb    = (float*)(ws + 32 * MB);
    float* vb    = (float*)(ws + 48 * MB);
    u16*   h2    = (u16*)  (ws + 64 * MB);
    float* WqT   = (float*)(ws + 72 * MB);
    float* WkT   = (float*)(ws + 76 * MB);
    float* WvT   = (float*)(ws + 80 * MB);
    float* WoT   = (float*)(ws + 84 * MB);
    u16*   W1T   = (u16*)  (ws + 88 * MB);
    u16*   W2T   = (u16*)  (ws + 96 * MB);
    float* gates = (float*)(ws + 104 * MB);
    float* ctx   = h1;                      // overlays h1 (dead after QKV)
    float* x2    = qb;                      // overlays qb (dead after attn)
    u16*   up    = (u16*)  (ws + 32 * MB);  // overlays kb+vb (dead after attn)

    // weight transposes: fp32 for the attention trunk, bf16 for the MoE
    transpose_f2f_kernel<<<dim3(32, 32, 1), 256, 0, stream>>>(Wq, WqT, 1024, 1024);
    transpose_f2f_kernel<<<dim3(32, 32, 1), 256, 0, stream>>>(Wk, WkT, 1024, 1024);
    transpose_f2f_kernel<<<dim3(32, 32, 1), 256, 0, stream>>>(Wv, WvT, 1024, 1024);
    transpose_f2f_kernel<<<dim3(32, 32, 1), 256, 0, stream>>>(Wo, WoT, 1024, 1024);
    transpose_f2b_kernel<<<dim3(8, 32, 16), 256, 0, stream>>>(W1, W1T, 1024, 256);
    transpose_f2b_kernel<<<dim3(32, 128, 1), 256, 0, stream>>>(W2, W2T, 4096, 1024);

    // LN1: fp32 -> fp32 h1
    ln_f32_kernel<<<4096, 256, 0, stream>>>(x, ln1s, ln1b, h1);
    // QKV projections: split-fp32 GEMMs (fp32-accurate outputs)
    gemm_split<<<dim3(8, 32), 256, 0, stream>>>(h1, WqT, 4096, 1024, 1024, qb, 0, nullptr);
    gemm_split<<<dim3(8, 32), 256, 0, stream>>>(h1, WkT, 4096, 1024, 1024, kb, 0, nullptr);
    gemm_split<<<dim3(8, 32), 256, 0, stream>>>(h1, WvT, 4096, 1024, 1024, vb, 0, nullptr);
    // attention (fp32) -> ctx (overlays h1)
    attn_kernel<<<dim3(128, 32), 256, 0, stream>>>(qb, kb, vb, ctx);
    // output projection + residual: split-fp32 GEMM -> x2 (overlays qb)
    gemm_split<<<dim3(8, 32), 256, 0, stream>>>(ctx, WoT, 4096, 1024, 1024, x2, 1, x);
    // LN2: fp32 x2 -> bf16 h2
    ln_f2b_kernel<<<4096, 256, 0, stream>>>(x2, ln2s, ln2b, h2);
    // router (fp32 end-to-end) -> gates
    router_kernel<<<1024, 256, 0, stream>>>(x2, ln2s, ln2b, Wsel, gates);
    // MoE up (dense, relu*gate epilogue) -> up bf16 (overlays kb/vb)
    gemm_bt<<<dim3(32, 32), 256, 0, stream>>>(h2, W1T, 4096, 4096, 1024, up, 2, nullptr, gates);
    // MoE down + residual -> final fp32 output
    gemm_bt<<<dim3(8, 32), 256, 0, stream>>>(up, W2T, 4096, 1024, 4096, out, 1, x2, nullptr);
}

// Round 8
// 1072.499 us; speedup vs baseline: 1.8361x; 1.8361x over previous
//
#include <hip/hip_runtime.h>

typedef unsigned short u16;
typedef __attribute__((ext_vector_type(8))) short s16x8;
typedef __attribute__((ext_vector_type(4))) float f32x4;

__device__ __forceinline__ float bf2f(u16 u) {
    union { unsigned int i; float f; } c; c.i = ((unsigned int)u) << 16; return c.f;
}
__device__ __forceinline__ u16 f2bf(float f) {
    union { float f; unsigned int u; } c; c.f = f;
    unsigned int u = c.u;
    unsigned int r = (u + 0x7fffu + ((u >> 16) & 1u)) >> 16;
    return (u16)r;
}

// ------------- transpose fp32 -> fp32, 32x32 tiles -------------
__global__ __launch_bounds__(256) void transpose_f2f_kernel(const float* __restrict__ src,
                                                            float* __restrict__ dst,
                                                            int R, int C) {
    __shared__ float tile[32][33];
    int c0 = blockIdx.x * 32, r0 = blockIdx.y * 32;
    int tx = threadIdx.x & 31, ty = threadIdx.x >> 5;
    for (int i = 0; i < 4; i++)
        tile[ty + 8 * i][tx] = src[(size_t)(r0 + ty + 8 * i) * C + c0 + tx];
    __syncthreads();
    for (int i = 0; i < 4; i++)
        dst[(size_t)(c0 + ty + 8 * i) * R + r0 + tx] = tile[tx][ty + 8 * i];
}

// ------------- layernorm fp32 -> fp32 -------------
__global__ __launch_bounds__(256) void ln_f32_kernel(const float* __restrict__ x,
                                                     const float* __restrict__ sc,
                                                     const float* __restrict__ bi,
                                                     float* __restrict__ out) {
    int row = blockIdx.x, tid = threadIdx.x;
    f32x4 u = *(const f32x4*)(x + (size_t)row * 1024 + tid * 4);
    float s = u[0] + u[1] + u[2] + u[3];
    float ss = u[0]*u[0] + u[1]*u[1] + u[2]*u[2] + u[3]*u[3];
    for (int off = 1; off < 64; off <<= 1) { s += __shfl_xor(s, off, 64); ss += __shfl_xor(ss, off, 64); }
    __shared__ float red[8];
    if ((tid & 63) == 0) { red[tid >> 6] = s; red[4 + (tid >> 6)] = ss; }
    __syncthreads();
    s = red[0] + red[1] + red[2] + red[3];
    ss = red[4] + red[5] + red[6] + red[7];
    float mu = s * (1.0f / 1024.0f);
    float rstd = rsqrtf(ss * (1.0f / 1024.0f) - mu * mu + 1e-5f);
    f32x4 g = *(const f32x4*)(sc + tid * 4);
    f32x4 b = *(const f32x4*)(bi + tid * 4);
    float* op = out + (size_t)row * 1024 + tid * 4;
    for (int i = 0; i < 4; i++)
        op[i] = (u[i] - mu) * rstd * g[i] + b[i];
}

// ------------- layernorm fp32 -> bf16 (MoE GEMM input) -------------
__global__ __launch_bounds__(256) void ln_f2b_kernel(const float* __restrict__ x,
                                                     const float* __restrict__ sc,
                                                     const float* __restrict__ bi,
                                                     u16* __restrict__ out) {
    int row = blockIdx.x, tid = threadIdx.x;
    f32x4 u = *(const f32x4*)(x + (size_t)row * 1024 + tid * 4);
    float s = u[0] + u[1] + u[2] + u[3];
    float ss = u[0]*u[0] + u[1]*u[1] + u[2]*u[2] + u[3]*u[3];
    for (int off = 1; off < 64; off <<= 1) { s += __shfl_xor(s, off, 64); ss += __shfl_xor(ss, off, 64); }
    __shared__ float red[8];
    if ((tid & 63) == 0) { red[tid >> 6] = s; red[4 + (tid >> 6)] = ss; }
    __syncthreads();
    s = red[0] + red[1] + red[2] + red[3];
    ss = red[4] + red[5] + red[6] + red[7];
    float mu = s * (1.0f / 1024.0f);
    float rstd = rsqrtf(ss * (1.0f / 1024.0f) - mu * mu + 1e-5f);
    f32x4 g = *(const f32x4*)(sc + tid * 4);
    f32x4 b = *(const f32x4*)(bi + tid * 4);
    u16* op = out + (size_t)row * 1024 + tid * 4;
    for (int i = 0; i < 4; i++)
        op[i] = f2bf((u[i] - mu) * rstd * g[i] + b[i]);
}

// ------------- split-fp32 GEMM: C[M,N] = A[M,K] @ BT[N,K]^T, fp32 in -------------
// mode 1: fp32 C = acc + res[idx]
// mode 2: bf16 hi/lo split outputs Ch/Cl = split(acc * scale)    (QKV projections)
__global__ __launch_bounds__(256) void gemm_split(const float* __restrict__ A,
                                                  const float* __restrict__ BT,
                                                  int M, int N, int K,
                                                  float* __restrict__ C, int mode,
                                                  const float* __restrict__ res,
                                                  u16* __restrict__ Ch, u16* __restrict__ Cl,
                                                  float scale) {
    __shared__ __align__(16) short Ahs[128 * 32], Als[128 * 32];
    __shared__ __align__(16) short Bhs[128 * 32], Bls[128 * 32];
    int m0 = blockIdx.y * 128, n0 = blockIdx.x * 128;
    int tid = threadIdx.x, lane = tid & 63, w = tid >> 6;
    int wm = (w & 1) * 64, wn = (w >> 1) * 64;
    int lr = lane & 15, lq = lane >> 4;
    f32x4 acc[4][4] = {};

    for (int k0 = 0; k0 < K; k0 += 32) {
        for (int c = tid; c < 512; c += 256) {
            int row = c >> 2, col = (c & 3) * 8;
            const float* ap = &A[(size_t)(m0 + row) * K + k0 + col];
            const float* bp = &BT[(size_t)(n0 + row) * K + k0 + col];
            f32x4 a0 = *(const f32x4*)ap, a1 = *(const f32x4*)(ap + 4);
            f32x4 b0 = *(const f32x4*)bp, b1 = *(const f32x4*)(bp + 4);
            s16x8 ahv, alv, bhv, blv;
            for (int i = 0; i < 4; i++) {
                u16 h;
                h = f2bf(a0[i]); ahv[i]     = (short)h; alv[i]     = (short)f2bf(a0[i] - bf2f(h));
                h = f2bf(a1[i]); ahv[4 + i] = (short)h; alv[4 + i] = (short)f2bf(a1[i] - bf2f(h));
                h = f2bf(b0[i]); bhv[i]     = (short)h; blv[i]     = (short)f2bf(b0[i] - bf2f(h));
                h = f2bf(b1[i]); bhv[4 + i] = (short)h; blv[4 + i] = (short)f2bf(b1[i] - bf2f(h));
            }
            *(s16x8*)&Ahs[row * 32 + col] = ahv;
            *(s16x8*)&Als[row * 32 + col] = alv;
            *(s16x8*)&Bhs[row * 32 + col] = bhv;
            *(s16x8*)&Bls[row * 32 + col] = blv;
        }
        __syncthreads();
        s16x8 ah[4], al[4], bh[4], bl[4];
        for (int i = 0; i < 4; i++) {
            int off = (wm + i * 16 + lr) * 32 + lq * 8;
            ah[i] = *(const s16x8*)&Ahs[off];
            al[i] = *(const s16x8*)&Als[off];
        }
        for (int j = 0; j < 4; j++) {
            int off = (wn + j * 16 + lr) * 32 + lq * 8;
            bh[j] = *(const s16x8*)&Bhs[off];
            bl[j] = *(const s16x8*)&Bls[off];
        }
        for (int i = 0; i < 4; i++)
            for (int j = 0; j < 4; j++) {
                acc[i][j] = __builtin_amdgcn_mfma_f32_16x16x32_bf16(al[i], bh[j], acc[i][j], 0, 0, 0);
                acc[i][j] = __builtin_amdgcn_mfma_f32_16x16x32_bf16(ah[i], bl[j], acc[i][j], 0, 0, 0);
                acc[i][j] = __builtin_amdgcn_mfma_f32_16x16x32_bf16(ah[i], bh[j], acc[i][j], 0, 0, 0);
            }
        __syncthreads();
    }

    for (int i = 0; i < 4; i++)
        for (int j = 0; j < 4; j++)
            for (int r = 0; r < 4; r++) {
                int row = m0 + wm + i * 16 + lq * 4 + r;
                int col = n0 + wn + j * 16 + lr;
                size_t idx = (size_t)row * N + col;
                float v = acc[i][j][r];
                if (mode == 1) {
                    C[idx] = v + res[idx];
                } else {
                    v *= scale;
                    u16 hb = f2bf(v);
                    u16 lb = f2bf(v - bf2f(hb));
                    Ch[idx] = hb; Cl[idx] = lb;
                }
            }
}

// ------------- MoE GEMM: C[M,N] = A(bf16)[M,K] @ Bcat(fp32, [K][N]-flat rows) ----------
// mode 2 (up):   B = W1 [E,D,F]; n = e*256+f; bf16 C = relu(acc)*gates[row][n>>8]
// mode 1 (down): B = W2 flat [4096,1024];     fp32 C = acc + res[idx]
__global__ __launch_bounds__(256) void gemm_moe(const u16* __restrict__ A,
                                                const float* __restrict__ B,
                                                int M, int N, int K,
                                                void* __restrict__ C, int mode,
                                                const float* __restrict__ res,
                                                const float* __restrict__ gates) {
    __shared__ __align__(16) short As[128 * 32];
    __shared__ __align__(16) short Bs[128 * 32];
    int m0 = blockIdx.y * 128, n0 = blockIdx.x * 128;
    int tid = threadIdx.x, lane = tid & 63, w = tid >> 6;
    int wm = (w & 1) * 64, wn = (w >> 1) * 64;
    int lr = lane & 15, lq = lane >> 4;
    f32x4 acc[4][4] = {};

    for (int k0 = 0; k0 < K; k0 += 32) {
        // A: bf16 rows
        for (int c = tid; c < 512; c += 256) {
            int row = c >> 2, col = (c & 3) * 8;
            *(s16x8*)&As[row * 32 + col] = *(const s16x8*)&A[(size_t)(m0 + row) * K + k0 + col];
        }
        // B: fp32 rows (contiguous along n), convert + transpose into Bs[n][k]
        {
            int kk = tid >> 3, fseg = (tid & 7) * 16;
            const float* bp;
            if (mode == 2) bp = B + ((size_t)(n0 >> 8) * 1024 + k0 + kk) * 256 + (n0 & 255) + fseg;
            else           bp = B + (size_t)(k0 + kk) * 1024 + n0 + fseg;
            f32x4 b0 = *(const f32x4*)bp, b1 = *(const f32x4*)(bp + 4);
            f32x4 b2 = *(const f32x4*)(bp + 8), b3 = *(const f32x4*)(bp + 12);
            for (int i = 0; i < 4; i++) {
                Bs[(fseg + i)      * 32 + kk] = (short)f2bf(b0[i]);
                Bs[(fseg + 4 + i)  * 32 + kk] = (short)f2bf(b1[i]);
                Bs[(fseg + 8 + i)  * 32 + kk] = (short)f2bf(b2[i]);
                Bs[(fseg + 12 + i) * 32 + kk] = (short)f2bf(b3[i]);
            }
        }
        __syncthreads();
        s16x8 av[4], bv[4];
        for (int i = 0; i < 4; i++) av[i] = *(const s16x8*)&As[(wm + i * 16 + lr) * 32 + lq * 8];
        for (int j = 0; j < 4; j++) bv[j] = *(const s16x8*)&Bs[(wn + j * 16 + lr) * 32 + lq * 8];
        for (int i = 0; i < 4; i++)
            for (int j = 0; j < 4; j++)
                acc[i][j] = __builtin_amdgcn_mfma_f32_16x16x32_bf16(av[i], bv[j], acc[i][j], 0, 0, 0);
        __syncthreads();
    }

    for (int i = 0; i < 4; i++)
        for (int j = 0; j < 4; j++)
            for (int r = 0; r < 4; r++) {
                int row = m0 + wm + i * 16 + lq * 4 + r;
                int col = n0 + wn + j * 16 + lr;
                size_t idx = (size_t)row * N + col;
                float v = acc[i][j][r];
                if (mode == 1) {
                    ((float*)C)[idx] = v + res[idx];
                } else {
                    float g = gates[(size_t)row * 16 + (col >> 8)];
                    ((u16*)C)[idx] = f2bf(fmaxf(v, 0.0f) * g);
                }
            }
}

// ------------- V transpose: v_hi/lo [4096][1024] -> vT_hi/lo [32 bh][64 d][2048 s] -------
__global__ __launch_bounds__(256) void vtrans_kernel(const u16* __restrict__ v_hi,
                                                     const u16* __restrict__ v_lo,
                                                     u16* __restrict__ vT_hi,
                                                     u16* __restrict__ vT_lo) {
    __shared__ __align__(16) short tile[64][72];
    int st = blockIdx.x, bh = blockIdx.y;
    int b = bh >> 4, h = bh & 15;
    int tid = threadIdx.x;
    int i = tid >> 2, seg = (tid & 3) * 16;
    for (int p = 0; p < 2; p++) {
        const u16* src = p ? v_lo : v_hi;
        u16* dst = p ? vT_lo : vT_hi;
        size_t goff = (size_t)(b * 2048 + st * 64 + i) * 1024 + h * 64 + seg;
        *(s16x8*)&tile[i][seg]     = *(const s16x8*)&src[goff];
        *(s16x8*)&tile[i][seg + 8] = *(const s16x8*)&src[goff + 8];
        __syncthreads();
        s16x8 o0, o1;
        for (int j = 0; j < 8; j++) { o0[j] = tile[seg + j][i]; o1[j] = tile[seg + 8 + j][i]; }
        size_t doff = ((size_t)bh * 64 + i) * 2048 + st * 64 + seg;
        *(s16x8*)&dst[doff]     = o0;
        *(s16x8*)&dst[doff + 8] = o1;
        __syncthreads();
    }
}

// ------------- MFMA flash attention, split-bf16 (4-term), online softmax -------------
// grid (16, 32): block = 128 Q rows of one (b,h); 4 waves x 32 rows (2 row-tiles).
// K/V chunks of 64 keys. Q pre-scaled by 1/8 at split time.
__global__ __launch_bounds__(256) void attn_mfma(const u16* __restrict__ qh_g,
                                                 const u16* __restrict__ ql_g,
                                                 const u16* __restrict__ kh_g,
                                                 const u16* __restrict__ kl_g,
                                                 const u16* __restrict__ vth_g,
                                                 const u16* __restrict__ vtl_g,
                                                 float* __restrict__ ctx) {
    __shared__ __align__(16) short Ksh[64][72], Ksl[64][72], Vsh[64][72], Vsl[64][72];
    __shared__ __align__(16) short Ph[4][16][72], Pl[4][16][72];
    int bh = blockIdx.y, b = bh >> 4, h = bh & 15;
    int tid = threadIdx.x, w = tid >> 6, lane = tid & 63;
    int lr = lane & 15, lq = lane >> 4;
    int qbase = blockIdx.x * 128 + w * 32;

    // preload Q fragments (A-layout: A[m=lane&15][k=lq*8+j])
    s16x8 qfh[2][2], qfl[2][2];
    for (int rt = 0; rt < 2; rt++)
        for (int kc = 0; kc < 2; kc++) {
            size_t qoff = (size_t)(b * 2048 + qbase + rt * 16 + lr) * 1024 + h * 64 + kc * 32 + lq * 8;
            qfh[rt][kc] = *(const s16x8*)&qh_g[qoff];
            qfl[rt][kc] = *(const s16x8*)&ql_g[qoff];
        }

    float m_[2][4], l_[2][4];
    f32x4 O[2][4] = {};
    for (int rt = 0; rt < 2; rt++)
        for (int r = 0; r < 4; r++) { m_[rt][r] = -1e30f; l_[rt][r] = 0.0f; }

    for (int kc0 = 0; kc0 < 2048; kc0 += 64) {
        {   // stage K chunk [key][d] and V^T chunk [d][key]
            int kk = tid >> 2, seg = (tid & 3) * 16;
            size_t goff = (size_t)(b * 2048 + kc0 + kk) * 1024 + h * 64 + seg;
            *(s16x8*)&Ksh[kk][seg]     = *(const s16x8*)&kh_g[goff];
            *(s16x8*)&Ksh[kk][seg + 8] = *(const s16x8*)&kh_g[goff + 8];
            *(s16x8*)&Ksl[kk][seg]     = *(const s16x8*)&kl_g[goff];
            *(s16x8*)&Ksl[kk][seg + 8] = *(const s16x8*)&kl_g[goff + 8];
            size_t voff = ((size_t)bh * 64 + kk) * 2048 + kc0 + seg;
            *(s16x8*)&Vsh[kk][seg]     = *(const s16x8*)&vth_g[voff];
            *(s16x8*)&Vsh[kk][seg + 8] = *(const s16x8*)&vth_g[voff + 8];
            *(s16x8*)&Vsl[kk][seg]     = *(const s16x8*)&vtl_g[voff];
            *(s16x8*)&Vsl[kk][seg + 8] = *(const s16x8*)&vtl_g[voff + 8];
        }
        __syncthreads();

        // S = Q K^T (4-term split)
        f32x4 s[2][4];
        for (int rt = 0; rt < 2; rt++)
            for (int ct = 0; ct < 4; ct++) {
                f32x4 a = {0.0f, 0.0f, 0.0f, 0.0f};
                for (int kc = 0; kc < 2; kc++) {
                    s16x8 kbh = *(const s16x8*)&Ksh[ct * 16 + lr][kc * 32 + lq * 8];
                    s16x8 kbl = *(const s16x8*)&Ksl[ct * 16 + lr][kc * 32 + lq * 8];
                    a = __builtin_amdgcn_mfma_f32_16x16x32_bf16(qfl[rt][kc], kbl, a, 0, 0, 0);
                    a = __builtin_amdgcn_mfma_f32_16x16x32_bf16(qfl[rt][kc], kbh, a, 0, 0, 0);
                    a = __builtin_amdgcn_mfma_f32_16x16x32_bf16(qfh[rt][kc], kbl, a, 0, 0, 0);
                    a = __builtin_amdgcn_mfma_f32_16x16x32_bf16(qfh[rt][kc], kbh, a, 0, 0, 0);
                }
                s[rt][ct] = a;
            }

        // online softmax + P V per row-tile (P LDS buffer reused across rt, same wave)
        for (int rt = 0; rt < 2; rt++) {
            float al[4];
            for (int ri = 0; ri < 4; ri++) {
                float mx = fmaxf(fmaxf(s[rt][0][ri], s[rt][1][ri]), fmaxf(s[rt][2][ri], s[rt][3][ri]));
                for (int off = 1; off < 16; off <<= 1) mx = fmaxf(mx, __shfl_xor(mx, off, 64));
                float mn = fmaxf(m_[rt][ri], mx);
                float a = __expf(m_[rt][ri] - mn);
                m_[rt][ri] = mn; al[ri] = a;
                float ps = 0.0f;
                for (int ct = 0; ct < 4; ct++) {
                    float p = __expf(s[rt][ct][ri] - mn);
                    s[rt][ct][ri] = p; ps += p;
                }
                for (int off = 1; off < 16; off <<= 1) ps += __shfl_xor(ps, off, 64);
                l_[rt][ri] = l_[rt][ri] * a + ps;
            }
            for (int nt = 0; nt < 4; nt++)
                for (int ri = 0; ri < 4; ri++) O[rt][nt][ri] *= al[ri];
            // split P (RNE) and round-trip through LDS to A-layout.
            // BARRIER before the cross-lane read: forces s_waitcnt lgkmcnt(0) so all
            // lanes' ds_writes are complete/visible (round-7 ran without it and
            // diverged on hot replays — timing-dependent LDS RAW hazard).
            for (int ct = 0; ct < 4; ct++)
                for (int ri = 0; ri < 4; ri++) {
                    float p = s[rt][ct][ri];
                    u16 hb = f2bf(p);
                    u16 lb = f2bf(p - bf2f(hb));
                    int row = lq * 4 + ri, col = ct * 16 + lr;
                    Ph[w][row][col] = (short)hb;
                    Pl[w][row][col] = (short)lb;
                }
            __syncthreads();
            for (int kc = 0; kc < 2; kc++) {
                s16x8 pah = *(const s16x8*)&Ph[w][lr][kc * 32 + lq * 8];
                s16x8 pal = *(const s16x8*)&Pl[w][lr][kc * 32 + lq * 8];
                for (int nt = 0; nt < 4; nt++) {
                    s16x8 vbh = *(const s16x8*)&Vsh[nt * 16 + lr][kc * 32 + lq * 8];
                    s16x8 vbl = *(const s16x8*)&Vsl[nt * 16 + lr][kc * 32 + lq * 8];
                    O[rt][nt] = __builtin_amdgcn_mfma_f32_16x16x32_bf16(pal, vbl, O[rt][nt], 0, 0, 0);
                    O[rt][nt] = __builtin_amdgcn_mfma_f32_16x16x32_bf16(pal, vbh, O[rt][nt], 0, 0, 0);
                    O[rt][nt] = __builtin_amdgcn_mfma_f32_16x16x32_bf16(pah, vbl, O[rt][nt], 0, 0, 0);
                    O[rt][nt] = __builtin_amdgcn_mfma_f32_16x16x32_bf16(pah, vbh, O[rt][nt], 0, 0, 0);
                }
            }
            __syncthreads();   // P reads done before next rt/chunk rewrites Ph/Pl
        }
    }

    for (int rt = 0; rt < 2; rt++)
        for (int nt = 0; nt < 4; nt++)
            for (int ri = 0; ri < 4; ri++) {
                int row = qbase + rt * 16 + lq * 4 + ri;
                int d = nt * 16 + lr;
                ctx[(size_t)(b * 2048 + row) * 1024 + h * 64 + d] = O[rt][nt][ri] / l_[rt][ri];
            }
}

// ------------- router: pure fp32 (decisions must match fp32 reference) -------------
__global__ __launch_bounds__(256) void router_kernel(const float* __restrict__ x2,
                                                     const float* __restrict__ sc,
                                                     const float* __restrict__ bi,
                                                     const float* __restrict__ Wsel,
                                                     float* __restrict__ gates) {
    int tid = threadIdx.x, w = tid >> 6, lane = tid & 63;
    int t = blockIdx.x * 4 + w;
    const float* xp = x2 + (size_t)t * 1024;
    float s = 0.0f, ss = 0.0f;
    for (int i = 0; i < 16; i++) {
        float v = xp[lane * 16 + i];
        s += v; ss += v * v;
    }
    for (int off = 1; off < 64; off <<= 1) { s += __shfl_xor(s, off, 64); ss += __shfl_xor(ss, off, 64); }
    float mu = s * (1.0f / 1024.0f);
    float rstd = rsqrtf(ss * (1.0f / 1024.0f) - mu * mu + 1e-5f);
    int e = lane & 15, part = lane >> 4;
    float acc = 0.0f;
    for (int d = part * 256; d < part * 256 + 256; d++) {
        float h = (xp[d] - mu) * rstd * sc[d] + bi[d];
        acc += h * Wsel[(size_t)d * 16 + e];
    }
    acc += __shfl_xor(acc, 16, 64);
    acc += __shfl_xor(acc, 32, 64);
    float v = 1.0f / (1.0f + __expf(-acc));
    float m1 = v;
    for (int off = 1; off < 64; off <<= 1) m1 = fmaxf(m1, __shfl_xor(m1, off, 64));
    unsigned long long b1 = __ballot(v == m1);
    int e1 = (__ffsll(b1) - 1) & 15;
    float v2 = (e == e1) ? -1e30f : v;
    float m2 = v2;
    for (int off = 1; off < 64; off <<= 1) m2 = fmaxf(m2, __shfl_xor(m2, off, 64));
    unsigned long long b2 = __ballot(v2 == m2);
    int e2 = (__ffsll(b2) - 1) & 15;
    if (lane < 16)
        gates[(size_t)t * 16 + e] = (e == e1) ? m1 : (e == e2 ? m2 : 0.0f);
}

extern "C" void kernel_launch(void* const* d_in, const int* in_sizes, int n_in,
                              void* d_out, int out_size, void* d_ws, size_t ws_size,
                              hipStream_t stream) {
    const float* x    = (const float*)d_in[0];
    const float* Wq   = (const float*)d_in[1];
    const float* Wk   = (const float*)d_in[2];
    const float* Wv   = (const float*)d_in[3];
    const float* Wo   = (const float*)d_in[4];
    const float* ln1s = (const float*)d_in[5];
    const float* ln1b = (const float*)d_in[6];
    const float* ln2s = (const float*)d_in[7];
    const float* ln2b = (const float*)d_in[8];
    const float* Wsel = (const float*)d_in[9];
    const float* W1   = (const float*)d_in[10];
    const float* W2   = (const float*)d_in[11];
    float* out = (float*)d_out;

    // Workspace (96 MB total, liveness-overlaid):
    //  [0,16)  h1 fp32 (ln1) -> vT_hi[0,8)/vT_lo[8,16) -> h2 bf16 [0,8) + gates [8,8.25)
    //  [16,48) q_hi/q_lo/k_hi/k_lo bf16 -> up bf16 after attn
    //  [48,64) v_hi/v_lo bf16 -> ctx fp32 after vtrans
    //  [64,80) x2 fp32 (live to end)
    //  [80,96) WqT/WkT/WvT/WoT fp32
    char* ws = (char*)d_ws;
    const size_t MB = 1024 * 1024;
    float* h1    = (float*)(ws + 0 * MB);
    u16*   vT_hi = (u16*)  (ws + 0 * MB);
    u16*   vT_lo = (u16*)  (ws + 8 * MB);
    u16*   h2    = (u16*)  (ws + 0 * MB);
    float* gates = (float*)(ws + 8 * MB);
    u16*   q_hi  = (u16*)  (ws + 16 * MB);
    u16*   q_lo  = (u16*)  (ws + 24 * MB);
    u16*   k_hi  = (u16*)  (ws + 32 * MB);
    u16*   k_lo  = (u16*)  (ws + 40 * MB);
    u16*   up    = (u16*)  (ws + 16 * MB);
    u16*   v_hi  = (u16*)  (ws + 48 * MB);
    u16*   v_lo  = (u16*)  (ws + 56 * MB);
    float* ctx   = (float*)(ws + 48 * MB);
    float* x2    = (float*)(ws + 64 * MB);
    float* WqT   = (float*)(ws + 80 * MB);
    float* WkT   = (float*)(ws + 84 * MB);
    float* WvT   = (float*)(ws + 88 * MB);
    float* WoT   = (float*)(ws + 92 * MB);

    transpose_f2f_kernel<<<dim3(32, 32), 256, 0, stream>>>(Wq, WqT, 1024, 1024);
    transpose_f2f_kernel<<<dim3(32, 32), 256, 0, stream>>>(Wk, WkT, 1024, 1024);
    transpose_f2f_kernel<<<dim3(32, 32), 256, 0, stream>>>(Wv, WvT, 1024, 1024);
    transpose_f2f_kernel<<<dim3(32, 32), 256, 0, stream>>>(Wo, WoT, 1024, 1024);

    // LN1 -> h1 fp32
    ln_f32_kernel<<<4096, 256, 0, stream>>>(x, ln1s, ln1b, h1);
    // QKV projections -> bf16 hi/lo splits (Q pre-scaled by 1/8)
    gemm_split<<<dim3(8, 32), 256, 0, stream>>>(h1, WqT, 4096, 1024, 1024, nullptr, 2, nullptr, q_hi, q_lo, 0.125f);
    gemm_split<<<dim3(8, 32), 256, 0, stream>>>(h1, WkT, 4096, 1024, 1024, nullptr, 2, nullptr, k_hi, k_lo, 1.0f);
    gemm_split<<<dim3(8, 32), 256, 0, stream>>>(h1, WvT, 4096, 1024, 1024, nullptr, 2, nullptr, v_hi, v_lo, 1.0f);
    // V -> V^T per (b,h)
    vtrans_kernel<<<dim3(32, 32), 256, 0, stream>>>(v_hi, v_lo, vT_hi, vT_lo);
    // MFMA flash attention -> ctx fp32
    attn_mfma<<<dim3(16, 32), 256, 0, stream>>>(q_hi, q_lo, k_hi, k_lo, vT_hi, vT_lo, ctx);
    // output projection + residual -> x2 fp32
    gemm_split<<<dim3(8, 32), 256, 0, stream>>>(ctx, WoT, 4096, 1024, 1024, x2, 1, x, nullptr, nullptr, 1.0f);
    // LN2 -> h2 bf16
    ln_f2b_kernel<<<4096, 256, 0, stream>>>(x2, ln2s, ln2b, h2);
    // router -> gates
    router_kernel<<<1024, 256, 0, stream>>>(x2, ln2s, ln2b, Wsel, gates);
    // MoE up (dense, relu*gate) -> up bf16
    gemm_moe<<<dim3(32, 32), 256, 0, stream>>>(h2, W1, 4096, 4096, 1024, up, 2, nullptr, gates);
    // MoE down + residual -> out fp32
    gemm_moe<<<dim3(8, 32), 256, 0, stream>>>(up, W2, 4096, 1024, 4096, out, 1, x2, nullptr);
}